// Round 9
// baseline (550.129 us; speedup 1.0000x reference)
//
#include <hip/hip_runtime.h>
#include <hip/hip_fp16.h>

// ---------------------------------------------------------------------------
// HeteroGNN (2-layer bipartite GAT + fused output MLP).
// R9 = R7 (best, 487us) + fill critical-path surgery:
//  * atomicAdd issued immediately after the col load (overlaps ea loads+dots)
//  * nontemporal 8B scatter store (avoid write-allocate RMW line fetch)
// Everything else byte-identical to R7.
// ---------------------------------------------------------------------------

typedef _Float16 half4 __attribute__((ext_vector_type(4)));
typedef float f32x4 __attribute__((ext_vector_type(4)));

#define KCAP 48

__device__ __forceinline__ float wave_sum(float v){
#pragma unroll
  for (int off = 32; off; off >>= 1) v += __shfl_xor(v, off);
  return v;
}

// ---------- attention projection vectors ----------
__global__ __launch_bounds__(64) void precompute_vec_kernel(
    const float* __restrict__ Wsrc, const float* __restrict__ Wdst,
    const float* __restrict__ Wedge, const float* __restrict__ As,
    const float* __restrict__ Ad, const float* __restrict__ Ae,
    float* __restrict__ pv_as, float* __restrict__ pv_ad, float* __restrict__ pv_ae)
{
  int b = blockIdx.x;
  int lt = b / 272, rem = b - lt * 272;
  int lane = threadIdx.x;
  const float* W; const float* a; float* out;
  if (rem < 128)      { W = Wsrc  + lt*16384 + rem*128;       a = As + lt*128; out = pv_as + lt*128 + rem; }
  else if (rem < 256) { int d = rem-128; W = Wdst + lt*16384 + d*128; a = Ad + lt*128; out = pv_ad + lt*128 + d; }
  else                { int j = rem-256; W = Wedge + lt*2048 + j*128; a = Ae + lt*128; out = pv_ae + lt*16 + j; }
  float s = W[lane]*a[lane] + W[lane+64]*a[lane+64];
  s = wave_sum(s);
  if (lane == 0) *out = s;
}

// ---------- fuse output MLP weights ----------
__global__ void combine_linear_kernel(const float* __restrict__ lin0W, const float* __restrict__ lin0b,
                                      const float* __restrict__ lin1W, const float* __restrict__ lin1b,
                                      float* __restrict__ Wc, float* __restrict__ bc)
{
  int idx = blockIdx.x * 256 + threadIdx.x;
  if (idx < 2*128*64) {
    int t = idx / 8192; int r = (idx / 64) & 127; int o = idx & 63;
    const float* w0 = lin0W + t*16384 + r*128;
    const float* w1 = lin1W + t*8192 + o;
    float s = 0.f;
    for (int m = 0; m < 128; ++m) s += w0[m] * w1[m*64];
    Wc[idx] = s;
  } else if (idx < 2*128*64 + 128) {
    int q = idx - 16384; int t = q >> 6; int o = q & 63;
    const float* b0 = lin0b + t*128;
    const float* w1 = lin1W + t*8192 + o;
    float s = lin1b[t*64 + o];
    for (int m = 0; m < 128; ++m) s += b0[m] * w1[m*64];
    bc[q] = s;
  }
}

// ---------- build pre-swizzled fp16 W fragments ----------
__global__ __launch_bounds__(256) void wfrag_prep_kernel(
    const float* __restrict__ Wsrc, const float* __restrict__ pv_as,
    const float* __restrict__ pv_ad, const float* __restrict__ Wc,
    _Float16* __restrict__ Wf_conv, _Float16* __restrict__ Wf_mlp)
{
  int idx = blockIdx.x * 256 + threadIdx.x;
  if (idx < 73728) {
    int within = idx & 255;
    int l = within >> 2, i = within & 3;
    int rest = idx >> 8;
    int c = rest % 9; int rest2 = rest / 9;
    int s = rest2 & 7; int g = rest2 >> 3;
    int lg = g >> 1, who = g & 1;
    int k = s*16 + ((l>>4)<<2) + i;
    float val = 0.f;
    if (c < 8) {
      int col = c*16 + (l & 15);
      int lt = lg*2 + who;
      val = Wsrc[(size_t)lt*16384 + k*128 + col];
    } else {
      int cc = l & 15;
      if (cc == 0)      val = pv_as[(lg*2 + who)*128 + k];
      else if (cc == 1) val = pv_ad[(lg*2 + (who^1))*128 + k];
    }
    Wf_conv[idx] = (_Float16)val;
  } else {
    int q = idx - 73728;
    int within = q & 255;
    int l = within >> 2, i = within & 3;
    int rest = q >> 8;
    int c = rest & 3; int s = (rest >> 2) & 7; int m = rest >> 5;
    int k = s*16 + ((l>>4)<<2) + i;
    int col = c*16 + (l & 15);
    Wf_mlp[q] = (_Float16)Wc[m*8192 + k*64 + col];
  }
}

// ---------- device body: bucket fill (early atomic + nt scatter) ----------
__device__ __forceinline__ void fill_body(
    int fid, int tid,
    const int* __restrict__ ei0, const int* __restrict__ ei1,
    const float* __restrict__ ea0, const float* __restrict__ ea1,
    const float* __restrict__ pv_ae,
    int* __restrict__ cnt0, int* __restrict__ cnt1,
    uint2* __restrict__ bkt0, uint2* __restrict__ bkt1, int E, int gEf)
{
  int type = (fid >= gEf) ? 1 : 0;
  const int* ei = type ? ei1 : ei0;
  const float* ea = type ? ea1 : ea0;
  int* cnt = type ? cnt1 : cnt0;
  uint2* bkt = type ? bkt1 : bkt0;
  int e = (fid - type * gEf) * 256 + tid;
  if (e >= E) return;
  int col = ei[E + e];
  // issue the atomic FIRST: its round trip overlaps the src/ea loads + dots
  int pos = atomicAdd(&cnt[col], 1);
  int src = ei[e];
  const float4* er = (const float4*)(ea + (size_t)e * 16);
  float4 a0 = er[0], a1 = er[1], a2 = er[2], a3 = er[3];
  const float* v0 = pv_ae + type * 16;
  const float* v1 = pv_ae + (2 + type) * 16;
  float ae0 = a0.x*v0[0] + a0.y*v0[1] + a0.z*v0[2] + a0.w*v0[3]
            + a1.x*v0[4] + a1.y*v0[5] + a1.z*v0[6] + a1.w*v0[7]
            + a2.x*v0[8] + a2.y*v0[9] + a2.z*v0[10] + a2.w*v0[11]
            + a3.x*v0[12] + a3.y*v0[13] + a3.z*v0[14] + a3.w*v0[15];
  float ae1 = a0.x*v1[0] + a0.y*v1[1] + a0.z*v1[2] + a0.w*v1[3]
            + a1.x*v1[4] + a1.y*v1[5] + a1.z*v1[6] + a1.w*v1[7]
            + a2.x*v1[8] + a2.y*v1[9] + a2.z*v1[10] + a2.w*v1[11]
            + a3.x*v1[12] + a3.y*v1[13] + a3.z*v1[14] + a3.w*v1[15];
  if (pos < KCAP) {
    __half2 hh = __floats2half2_rn(ae0, ae1);
    unsigned long long val = (unsigned long long)(unsigned)src
                           | ((unsigned long long)(*(const unsigned*)&hh) << 32);
    __builtin_nontemporal_store(val,
        (unsigned long long*)&bkt[(size_t)col * KCAP + pos]);
  }
}

// ---------- device body: fp16 MFMA GEMM tile ----------
template<bool FIN, bool CONV>
__device__ __forceinline__ void gemm_body(_Float16* ldsb, int blk, int t,
    const void* __restrict__ Xv, const uint2* __restrict__ Wf,
    void* __restrict__ Hout, float* __restrict__ asrc, float* __restrict__ adst,
    const float* __restrict__ bias, int N)
{
  constexpr int NT = CONV ? 9 : 4;
  const int r0 = blk * 64;

  if (FIN) {
    const float* X = (const float*)Xv;
    for (int v = t; v < 2048; v += 256) {          // 64 rows x 32 chunks of 4
      int row = v >> 5, q = v & 31;
      int r = r0 + row;
      float4 xv = make_float4(0.f, 0.f, 0.f, 0.f);
      if (r < N) xv = *(const float4*)(X + (size_t)r * 128 + q * 4);
      _Float16* d = &ldsb[row * 136 + q * 4];
      d[0] = (_Float16)xv.x; d[1] = (_Float16)xv.y;
      d[2] = (_Float16)xv.z; d[3] = (_Float16)xv.w;
    }
  } else {
    const _Float16* X = (const _Float16*)Xv;
    for (int v = t; v < 1024; v += 256) {          // 64 rows x 16 chunks of 8
      int row = v >> 4, q = v & 15;
      int r = r0 + row;
      uint4 xv = make_uint4(0u, 0u, 0u, 0u);
      if (r < N) xv = *(const uint4*)(X + (size_t)r * 128 + q * 8);
      *(uint4*)(&ldsb[row * 136 + q * 8]) = xv;
    }
  }
  __syncthreads();

  const int w = t >> 6, l = t & 63;
  f32x4 acc[NT];
#pragma unroll
  for (int c = 0; c < NT; ++c) acc[c] = (f32x4)(0.f);

  const uint2* wp = Wf + l;
  const int aoff = (w * 16 + (l & 15)) * 136 + ((l >> 4) << 2);
#pragma unroll
  for (int s = 0; s < 8; ++s) {
    half4 af = *(const half4*)(&ldsb[aoff + s * 16]);
#pragma unroll
    for (int c = 0; c < NT; ++c) {
      uint2 bw = wp[(s * NT + c) * 64];
      half4 bf = *reinterpret_cast<const half4*>(&bw);
      acc[c] = __builtin_amdgcn_mfma_f32_16x16x16f16(af, bf, acc[c], 0, 0, 0);
    }
  }
  __syncthreads();

  if (CONV) {
#pragma unroll
    for (int c = 0; c < 8; ++c)
#pragma unroll
      for (int rg = 0; rg < 4; ++rg)
        ldsb[(w*16 + ((l>>4)<<2) + rg) * 136 + c*16 + (l & 15)] = (_Float16)acc[c][rg];
    if ((l & 15) < 2) {
      float* dst = ((l & 15) == 0) ? asrc : adst;
#pragma unroll
      for (int rg = 0; rg < 4; ++rg) {
        int r = r0 + w*16 + ((l>>4)<<2) + rg;
        if (r < N) dst[r] = acc[8][rg];
      }
    }
    __syncthreads();
    _Float16* H = (_Float16*)Hout;
    for (int v = t; v < 1024; v += 256) {
      int row = v >> 4, q = v & 15;
      int r = r0 + row;
      if (r < N)
        *(uint4*)(H + (size_t)r * 128 + q * 8) = *(const uint4*)(&ldsb[row * 136 + q * 8]);
    }
  } else {
    float* ldsf = (float*)ldsb;  // [64][68]
#pragma unroll
    for (int c = 0; c < 4; ++c)
#pragma unroll
      for (int rg = 0; rg < 4; ++rg)
        ldsf[(w*16 + ((l>>4)<<2) + rg) * 68 + c*16 + (l & 15)] = acc[c][rg];
    __syncthreads();
    float* O = (float*)Hout;
    for (int v = t; v < 1024; v += 256) {
      int row = v >> 4, q = v & 15;
      int r = r0 + row;
      if (r < N) {
        float4 o = *(const float4*)(&ldsf[row * 68 + q * 4]);
        float4 bb = *(const float4*)(bias + q * 4);
        o.x += bb.x; o.y += bb.y; o.z += bb.z; o.w += bb.w;
        *(float4*)(O + (size_t)r * 64 + q * 4) = o;
      }
    }
  }
}

// ---------- phase0: bucket fill + both layer-0 GEMMs, interleaved ----------
__global__ __launch_bounds__(256) void phase0_kernel(
    const float* __restrict__ xu, const float* __restrict__ xi,
    const uint2* __restrict__ Wfc,
    _Float16* __restrict__ hs_u, _Float16* __restrict__ hs_i,
    float* __restrict__ asrc_u, float* __restrict__ adst_u,
    float* __restrict__ asrc_i, float* __restrict__ adst_i,
    const int* __restrict__ ei0, const int* __restrict__ ei1,
    const float* __restrict__ ea0, const float* __restrict__ ea1,
    const float* __restrict__ pv_ae,
    int* __restrict__ cnt0, int* __restrict__ cnt1,
    uint2* __restrict__ bkt0, uint2* __restrict__ bkt1,
    int N, int E, int gB, int P, int gEf)
{
  __shared__ __align__(16) _Float16 ldsb[64 * 136];
  int b = blockIdx.x, t = threadIdx.x;
  int g = b / P, r = b - g * P;
  if (r == 0) {  // g in [0, 2*gB)
    if (g < gB)
      gemm_body<true, true>(ldsb, g, t, xu, Wfc, hs_u, asrc_u, adst_u, nullptr, N);
    else
      gemm_body<true, true>(ldsb, g - gB, t, xi, Wfc + 4608, hs_i, asrc_i, adst_i, nullptr, N);
  } else {
    int fid = b - g - 1;
    if (fid < 2 * gEf)
      fill_body(fid, t, ei0, ei1, ea0, ea1, pv_ae, cnt0, cnt1, bkt0, bkt1, E, gEf);
  }
}

// ---------- fused GEMM pair ----------
template<bool FIN, bool CONV>
__global__ __launch_bounds__(256) void gemm_pair_kernel(
    const void* __restrict__ X0, const void* __restrict__ X1,
    const uint2* __restrict__ Wf0, const uint2* __restrict__ Wf1,
    void* __restrict__ H0, void* __restrict__ H1,
    float* __restrict__ asrc0, float* __restrict__ adst0,
    float* __restrict__ asrc1, float* __restrict__ adst1,
    const float* __restrict__ bias0, const float* __restrict__ bias1,
    int N, int gB)
{
  __shared__ __align__(16) _Float16 ldsb[64 * 136];
  int b = blockIdx.x;
  if (b < gB)
    gemm_body<FIN, CONV>(ldsb, b, threadIdx.x, X0, Wf0, H0, asrc0, adst0, bias0, N);
  else
    gemm_body<FIN, CONV>(ldsb, b - gB, threadIdx.x, X1, Wf1, H1, asrc1, adst1, bias1, N);
}

// ---------- fused aggregate pair: 16B/lane gathers, 4 edges per load ----------
__global__ __launch_bounds__(256) void aggregate_pair(
    const int* __restrict__ cnt0, const uint2* __restrict__ bkt0,
    const float* __restrict__ asrc0, const float* __restrict__ adst0,
    const __half2* __restrict__ hs0, const float* __restrict__ bias0,
    __half2* __restrict__ out0,
    const int* __restrict__ cnt1, const uint2* __restrict__ bkt1,
    const float* __restrict__ asrc1, const float* __restrict__ adst1,
    const __half2* __restrict__ hs1, const float* __restrict__ bias1,
    __half2* __restrict__ out1,
    int N, int lsel, int gHalf)
{
  int b = blockIdx.x;
  int tt = (b >= gHalf) ? 1 : 0;
  const int* cnt_tab    = tt ? cnt1 : cnt0;
  const uint2* bkt      = tt ? bkt1 : bkt0;
  const float* asrc_tab = tt ? asrc1 : asrc0;
  const float* adst_tab = tt ? adst1 : adst0;
  const uint4* hs4      = (const uint4*)(tt ? hs1 : hs0);  // row = 16 uint4
  const float* bias     = tt ? bias1 : bias0;
  __half2* xnew         = tt ? out1 : out0;

  int wid = threadIdx.x >> 6, lane = threadIdx.x & 63;
  int n = (b - tt * gHalf) * 4 + wid;
  if (n >= N) return;
  int cnt = cnt_tab[n]; if (cnt > KCAP) cnt = KCAP;
  float adst = adst_tab[n];

  // one bucket entry per lane (cnt <= KCAP=48 <= 64)
  int r = 0; float wgt = 0.f;
  if (lane < cnt) {
    uint2 sv = bkt[(size_t)n * KCAP + lane];
    r = (int)sv.x;
    __half2 hh = *(const __half2*)&sv.y;
    float ae = lsel ? __high2float(hh) : __low2float(hh);
    float al = asrc_tab[r] + adst + ae;
    al = (al > 0.f) ? al : 0.2f * al;
    wgt = __expf(al);
  }

  const int quarter = lane >> 4;   // which of 4 edges this lane serves
  const int j = lane & 15;         // uint4 column (8 halfs)
  float acc[8];
#pragma unroll
  for (int q = 0; q < 8; ++q) acc[q] = 0.f;

  int k = 0;
  for (; k + 8 <= cnt; k += 8) {
    int   rr0 = __shfl(r,   k + quarter);
    float ww0 = __shfl(wgt, k + quarter);
    int   rr1 = __shfl(r,   k + 4 + quarter);
    float ww1 = __shfl(wgt, k + 4 + quarter);
    uint4 v0 = hs4[(size_t)rr0 * 16 + j];
    uint4 v1 = hs4[(size_t)rr1 * 16 + j];
    float2 f;
    f = __half22float2(*(const __half2*)&v0.x); acc[0]=fmaf(ww0,f.x,acc[0]); acc[1]=fmaf(ww0,f.y,acc[1]);
    f = __half22float2(*(const __half2*)&v0.y); acc[2]=fmaf(ww0,f.x,acc[2]); acc[3]=fmaf(ww0,f.y,acc[3]);
    f = __half22float2(*(const __half2*)&v0.z); acc[4]=fmaf(ww0,f.x,acc[4]); acc[5]=fmaf(ww0,f.y,acc[5]);
    f = __half22float2(*(const __half2*)&v0.w); acc[6]=fmaf(ww0,f.x,acc[6]); acc[7]=fmaf(ww0,f.y,acc[7]);
    f = __half22float2(*(const __half2*)&v1.x); acc[0]=fmaf(ww1,f.x,acc[0]); acc[1]=fmaf(ww1,f.y,acc[1]);
    f = __half22float2(*(const __half2*)&v1.y); acc[2]=fmaf(ww1,f.x,acc[2]); acc[3]=fmaf(ww1,f.y,acc[3]);
    f = __half22float2(*(const __half2*)&v1.z); acc[4]=fmaf(ww1,f.x,acc[4]); acc[5]=fmaf(ww1,f.y,acc[5]);
    f = __half22float2(*(const __half2*)&v1.w); acc[6]=fmaf(ww1,f.x,acc[6]); acc[7]=fmaf(ww1,f.y,acc[7]);
  }
  for (; k < cnt; k += 4) {
    // lanes whose edge index k+quarter >= cnt read lane with wgt==0 -> no-op
    int   rr = __shfl(r,   k + quarter);
    float ww = __shfl(wgt, k + quarter);
    uint4 v = hs4[(size_t)rr * 16 + j];
    float2 f;
    f = __half22float2(*(const __half2*)&v.x); acc[0]=fmaf(ww,f.x,acc[0]); acc[1]=fmaf(ww,f.y,acc[1]);
    f = __half22float2(*(const __half2*)&v.y); acc[2]=fmaf(ww,f.x,acc[2]); acc[3]=fmaf(ww,f.y,acc[3]);
    f = __half22float2(*(const __half2*)&v.z); acc[4]=fmaf(ww,f.x,acc[4]); acc[5]=fmaf(ww,f.y,acc[5]);
    f = __half22float2(*(const __half2*)&v.w); acc[6]=fmaf(ww,f.x,acc[6]); acc[7]=fmaf(ww,f.y,acc[7]);
  }

#pragma unroll
  for (int q = 0; q < 8; ++q) {
    acc[q] += __shfl_xor(acc[q], 16);
    acc[q] += __shfl_xor(acc[q], 32);
  }
  float den = wave_sum(wgt);
  float inv = (den > 0.f) ? 1.f / den : 0.f;

  if (quarter == 0) {
    float4 b0 = *(const float4*)(bias + 8*j);
    float4 b1 = *(const float4*)(bias + 8*j + 4);
    float o0 = fmaxf(fmaf(acc[0], inv, b0.x), 0.f);
    float o1 = fmaxf(fmaf(acc[1], inv, b0.y), 0.f);
    float o2 = fmaxf(fmaf(acc[2], inv, b0.z), 0.f);
    float o3 = fmaxf(fmaf(acc[3], inv, b0.w), 0.f);
    float o4 = fmaxf(fmaf(acc[4], inv, b1.x), 0.f);
    float o5 = fmaxf(fmaf(acc[5], inv, b1.y), 0.f);
    float o6 = fmaxf(fmaf(acc[6], inv, b1.z), 0.f);
    float o7 = fmaxf(fmaf(acc[7], inv, b1.w), 0.f);
    __half2 p0 = __floats2half2_rn(o0, o1);
    __half2 p1 = __floats2half2_rn(o2, o3);
    __half2 p2 = __floats2half2_rn(o4, o5);
    __half2 p3 = __floats2half2_rn(o6, o7);
    uint4 wv;
    wv.x = *(const unsigned*)&p0; wv.y = *(const unsigned*)&p1;
    wv.z = *(const unsigned*)&p2; wv.w = *(const unsigned*)&p3;
    ((uint4*)xnew)[(size_t)n * 16 + j] = wv;
  }
}

// ---------------------------------------------------------------------------
extern "C" void kernel_launch(void* const* d_in, const int* in_sizes, int n_in,
                              void* d_out, int out_size, void* d_ws, size_t ws_size,
                              hipStream_t stream)
{
  const float* x_user   = (const float*)d_in[0];
  const float* x_item   = (const float*)d_in[1];
  const float* ea_ui    = (const float*)d_in[2];
  const float* ea_iu    = (const float*)d_in[3];
  const float* W_src    = (const float*)d_in[4];
  const float* W_dst    = (const float*)d_in[5];
  const float* W_edge   = (const float*)d_in[6];
  const float* att_src  = (const float*)d_in[7];
  const float* att_dst  = (const float*)d_in[8];
  const float* att_edge = (const float*)d_in[9];
  const float* conv_bias= (const float*)d_in[10];
  const float* lin0W    = (const float*)d_in[11];
  const float* lin0b    = (const float*)d_in[12];
  const float* lin1W    = (const float*)d_in[13];
  const float* lin1b    = (const float*)d_in[14];
  const int*   ei_ui    = (const int*)d_in[15];
  const int*   ei_iu    = (const int*)d_in[16];

  const int N = in_sizes[0] / 128;
  const int E = in_sizes[15] / 2;

  char* p = (char*)d_ws;
  auto alloc = [&](size_t bytes) -> void* {
    void* r = (void*)p;
    p += (bytes + 255) & ~(size_t)255;
    return r;
  };
  _Float16* xu_a = (_Float16*)alloc((size_t)N * 128 * 2);
  _Float16* xi_a = (_Float16*)alloc((size_t)N * 128 * 2);
  _Float16* xu_b = (_Float16*)alloc((size_t)N * 128 * 2);
  _Float16* xi_b = (_Float16*)alloc((size_t)N * 128 * 2);
  _Float16* hs_u = (_Float16*)alloc((size_t)N * 128 * 2);
  _Float16* hs_i = (_Float16*)alloc((size_t)N * 128 * 2);
  uint2* bkt_ui  = (uint2*)alloc((size_t)N * KCAP * 8);
  uint2* bkt_iu  = (uint2*)alloc((size_t)N * KCAP * 8);
  int*   cnt_ui  = (int*)alloc((size_t)2 * N * 4);
  int*   cnt_iu  = cnt_ui + N;
  float* asrc_u  = (float*)alloc((size_t)N * 4);
  float* adst_u  = (float*)alloc((size_t)N * 4);
  float* asrc_i  = (float*)alloc((size_t)N * 4);
  float* adst_i  = (float*)alloc((size_t)N * 4);
  float* pv_as   = (float*)alloc(512 * 4);
  float* pv_ad   = (float*)alloc(512 * 4);
  float* pv_ae   = (float*)alloc(64 * 4);
  float* Wc      = (float*)alloc(2 * 128 * 64 * 4);
  float* bc      = (float*)alloc(128 * 4);
  _Float16* Wf_conv = (_Float16*)alloc(73728 * 2);
  _Float16* Wf_mlp  = (_Float16*)alloc(16384 * 2);

  // prep
  precompute_vec_kernel<<<4 * 272, 64, 0, stream>>>(W_src, W_dst, W_edge,
      att_src, att_dst, att_edge, pv_as, pv_ad, pv_ae);
  combine_linear_kernel<<<65, 256, 0, stream>>>(lin0W, lin0b, lin1W, lin1b, Wc, bc);
  wfrag_prep_kernel<<<352, 256, 0, stream>>>(W_src, pv_as, pv_ad, Wc, Wf_conv, Wf_mlp);
  hipMemsetAsync(cnt_ui, 0, (size_t)2 * N * 4, stream);

  const int gEf = (E + 255) / 256;
  const int gB  = (N + 63) / 64;
  const int GB2 = 2 * gB;
  const int P   = 1 + (2 * gEf + GB2 - 1) / GB2;   // 1 gemm block per (P-1) fill blocks
  const int gN4 = (N + 3) / 4;
  const uint2* Wfc = (const uint2*)Wf_conv;
  const uint2* Wfm = (const uint2*)Wf_mlp;

  // ---- phase 0: bucket fill + layer-0 GEMMs ----
  phase0_kernel<<<P * GB2, 256, 0, stream>>>(x_user, x_item, Wfc,
      hs_u, hs_i, asrc_u, adst_u, asrc_i, adst_i,
      ei_ui, ei_iu, ea_ui, ea_iu, pv_ae, cnt_ui, cnt_iu, bkt_ui, bkt_iu,
      N, E, gB, P, gEf);

  // ---- layer 0 aggregates (both types) ----
  aggregate_pair<<<2 * gN4, 256, 0, stream>>>(
      cnt_ui, bkt_ui, asrc_u, adst_i, (const __half2*)hs_u, conv_bias + 0*128, (__half2*)xi_a,
      cnt_iu, bkt_iu, asrc_i, adst_u, (const __half2*)hs_i, conv_bias + 1*128, (__half2*)xu_a,
      N, 0, gN4);

  // ---- layer 1 GEMMs (both types) ----
  gemm_pair_kernel<false, true><<<GB2, 256, 0, stream>>>(
      xu_a, xi_a, Wfc + 2*4608, Wfc + 3*4608, hs_u, hs_i,
      asrc_u, adst_u, asrc_i, adst_i, nullptr, nullptr, N, gB);

  // ---- layer 1 aggregates ----
  aggregate_pair<<<2 * gN4, 256, 0, stream>>>(
      cnt_ui, bkt_ui, asrc_u, adst_i, (const __half2*)hs_u, conv_bias + 2*128, (__half2*)xi_b,
      cnt_iu, bkt_iu, asrc_i, adst_u, (const __half2*)hs_i, conv_bias + 3*128, (__half2*)xu_b,
      N, 1, gN4);

  // ---- fused output MLP (both types) ----
  float* out = (float*)d_out;
  gemm_pair_kernel<false, false><<<GB2, 256, 0, stream>>>(
      xu_b, xi_b, Wfm, Wfm + 2048, out, out + (size_t)N * 64,
      nullptr, nullptr, nullptr, nullptr, bc, bc + 64, N, gB);
}

// Round 10
// 487.305 us; speedup vs baseline: 1.1289x; 1.1289x over previous
//
#include <hip/hip_runtime.h>
#include <hip/hip_fp16.h>

// ---------------------------------------------------------------------------
// HeteroGNN (2-layer bipartite GAT + fused output MLP).
// R10 = exact revert to R7 (best: 487us). R8 (4-edge fill: occupancy 40->25%)
// and R9 (early atomic + nontemporal store: forced waitcnt + uncached writes)
// both regressed phase0. Fill floor ~164-188us is empirically invariant across
// 5 structural variants; aggregates run at ~7.6TB/s effective L3 random BW.
// ---------------------------------------------------------------------------

typedef _Float16 half4 __attribute__((ext_vector_type(4)));
typedef float f32x4 __attribute__((ext_vector_type(4)));

#define KCAP 48

__device__ __forceinline__ float wave_sum(float v){
#pragma unroll
  for (int off = 32; off; off >>= 1) v += __shfl_xor(v, off);
  return v;
}

// ---------- attention projection vectors ----------
__global__ __launch_bounds__(64) void precompute_vec_kernel(
    const float* __restrict__ Wsrc, const float* __restrict__ Wdst,
    const float* __restrict__ Wedge, const float* __restrict__ As,
    const float* __restrict__ Ad, const float* __restrict__ Ae,
    float* __restrict__ pv_as, float* __restrict__ pv_ad, float* __restrict__ pv_ae)
{
  int b = blockIdx.x;
  int lt = b / 272, rem = b - lt * 272;
  int lane = threadIdx.x;
  const float* W; const float* a; float* out;
  if (rem < 128)      { W = Wsrc  + lt*16384 + rem*128;       a = As + lt*128; out = pv_as + lt*128 + rem; }
  else if (rem < 256) { int d = rem-128; W = Wdst + lt*16384 + d*128; a = Ad + lt*128; out = pv_ad + lt*128 + d; }
  else                { int j = rem-256; W = Wedge + lt*2048 + j*128; a = Ae + lt*128; out = pv_ae + lt*16 + j; }
  float s = W[lane]*a[lane] + W[lane+64]*a[lane+64];
  s = wave_sum(s);
  if (lane == 0) *out = s;
}

// ---------- fuse output MLP weights ----------
__global__ void combine_linear_kernel(const float* __restrict__ lin0W, const float* __restrict__ lin0b,
                                      const float* __restrict__ lin1W, const float* __restrict__ lin1b,
                                      float* __restrict__ Wc, float* __restrict__ bc)
{
  int idx = blockIdx.x * 256 + threadIdx.x;
  if (idx < 2*128*64) {
    int t = idx / 8192; int r = (idx / 64) & 127; int o = idx & 63;
    const float* w0 = lin0W + t*16384 + r*128;
    const float* w1 = lin1W + t*8192 + o;
    float s = 0.f;
    for (int m = 0; m < 128; ++m) s += w0[m] * w1[m*64];
    Wc[idx] = s;
  } else if (idx < 2*128*64 + 128) {
    int q = idx - 16384; int t = q >> 6; int o = q & 63;
    const float* b0 = lin0b + t*128;
    const float* w1 = lin1W + t*8192 + o;
    float s = lin1b[t*64 + o];
    for (int m = 0; m < 128; ++m) s += b0[m] * w1[m*64];
    bc[q] = s;
  }
}

// ---------- build pre-swizzled fp16 W fragments ----------
__global__ __launch_bounds__(256) void wfrag_prep_kernel(
    const float* __restrict__ Wsrc, const float* __restrict__ pv_as,
    const float* __restrict__ pv_ad, const float* __restrict__ Wc,
    _Float16* __restrict__ Wf_conv, _Float16* __restrict__ Wf_mlp)
{
  int idx = blockIdx.x * 256 + threadIdx.x;
  if (idx < 73728) {
    int within = idx & 255;
    int l = within >> 2, i = within & 3;
    int rest = idx >> 8;
    int c = rest % 9; int rest2 = rest / 9;
    int s = rest2 & 7; int g = rest2 >> 3;
    int lg = g >> 1, who = g & 1;
    int k = s*16 + ((l>>4)<<2) + i;
    float val = 0.f;
    if (c < 8) {
      int col = c*16 + (l & 15);
      int lt = lg*2 + who;
      val = Wsrc[(size_t)lt*16384 + k*128 + col];
    } else {
      int cc = l & 15;
      if (cc == 0)      val = pv_as[(lg*2 + who)*128 + k];
      else if (cc == 1) val = pv_ad[(lg*2 + (who^1))*128 + k];
    }
    Wf_conv[idx] = (_Float16)val;
  } else {
    int q = idx - 73728;
    int within = q & 255;
    int l = within >> 2, i = within & 3;
    int rest = q >> 8;
    int c = rest & 3; int s = (rest >> 2) & 7; int m = rest >> 5;
    int k = s*16 + ((l>>4)<<2) + i;
    int col = c*16 + (l & 15);
    Wf_mlp[q] = (_Float16)Wc[m*8192 + k*64 + col];
  }
}

// ---------- device body: bucket fill (single-pass, as R5/R7) ----------
__device__ __forceinline__ void fill_body(
    int fid, int tid,
    const int* __restrict__ ei0, const int* __restrict__ ei1,
    const float* __restrict__ ea0, const float* __restrict__ ea1,
    const float* __restrict__ pv_ae,
    int* __restrict__ cnt0, int* __restrict__ cnt1,
    uint2* __restrict__ bkt0, uint2* __restrict__ bkt1, int E, int gEf)
{
  int type = (fid >= gEf) ? 1 : 0;
  const int* ei = type ? ei1 : ei0;
  const float* ea = type ? ea1 : ea0;
  int* cnt = type ? cnt1 : cnt0;
  uint2* bkt = type ? bkt1 : bkt0;
  int e = (fid - type * gEf) * 256 + tid;
  if (e >= E) return;
  int src = ei[e], col = ei[E + e];
  const float4* er = (const float4*)(ea + (size_t)e * 16);
  float4 a0 = er[0], a1 = er[1], a2 = er[2], a3 = er[3];
  const float* v0 = pv_ae + type * 16;
  const float* v1 = pv_ae + (2 + type) * 16;
  float ae0 = a0.x*v0[0] + a0.y*v0[1] + a0.z*v0[2] + a0.w*v0[3]
            + a1.x*v0[4] + a1.y*v0[5] + a1.z*v0[6] + a1.w*v0[7]
            + a2.x*v0[8] + a2.y*v0[9] + a2.z*v0[10] + a2.w*v0[11]
            + a3.x*v0[12] + a3.y*v0[13] + a3.z*v0[14] + a3.w*v0[15];
  float ae1 = a0.x*v1[0] + a0.y*v1[1] + a0.z*v1[2] + a0.w*v1[3]
            + a1.x*v1[4] + a1.y*v1[5] + a1.z*v1[6] + a1.w*v1[7]
            + a2.x*v1[8] + a2.y*v1[9] + a2.z*v1[10] + a2.w*v1[11]
            + a3.x*v1[12] + a3.y*v1[13] + a3.z*v1[14] + a3.w*v1[15];
  int pos = atomicAdd(&cnt[col], 1);
  if (pos < KCAP) {
    __half2 hh = __floats2half2_rn(ae0, ae1);
    uint2 val;
    val.x = (unsigned)src;
    val.y = *(const unsigned*)&hh;
    bkt[(size_t)col * KCAP + pos] = val;
  }
}

// ---------- device body: fp16 MFMA GEMM tile ----------
template<bool FIN, bool CONV>
__device__ __forceinline__ void gemm_body(_Float16* ldsb, int blk, int t,
    const void* __restrict__ Xv, const uint2* __restrict__ Wf,
    void* __restrict__ Hout, float* __restrict__ asrc, float* __restrict__ adst,
    const float* __restrict__ bias, int N)
{
  constexpr int NT = CONV ? 9 : 4;
  const int r0 = blk * 64;

  if (FIN) {
    const float* X = (const float*)Xv;
    for (int v = t; v < 2048; v += 256) {          // 64 rows x 32 chunks of 4
      int row = v >> 5, q = v & 31;
      int r = r0 + row;
      float4 xv = make_float4(0.f, 0.f, 0.f, 0.f);
      if (r < N) xv = *(const float4*)(X + (size_t)r * 128 + q * 4);
      _Float16* d = &ldsb[row * 136 + q * 4];
      d[0] = (_Float16)xv.x; d[1] = (_Float16)xv.y;
      d[2] = (_Float16)xv.z; d[3] = (_Float16)xv.w;
    }
  } else {
    const _Float16* X = (const _Float16*)Xv;
    for (int v = t; v < 1024; v += 256) {          // 64 rows x 16 chunks of 8
      int row = v >> 4, q = v & 15;
      int r = r0 + row;
      uint4 xv = make_uint4(0u, 0u, 0u, 0u);
      if (r < N) xv = *(const uint4*)(X + (size_t)r * 128 + q * 8);
      *(uint4*)(&ldsb[row * 136 + q * 8]) = xv;
    }
  }
  __syncthreads();

  const int w = t >> 6, l = t & 63;
  f32x4 acc[NT];
#pragma unroll
  for (int c = 0; c < NT; ++c) acc[c] = (f32x4)(0.f);

  const uint2* wp = Wf + l;
  const int aoff = (w * 16 + (l & 15)) * 136 + ((l >> 4) << 2);
#pragma unroll
  for (int s = 0; s < 8; ++s) {
    half4 af = *(const half4*)(&ldsb[aoff + s * 16]);
#pragma unroll
    for (int c = 0; c < NT; ++c) {
      uint2 bw = wp[(s * NT + c) * 64];
      half4 bf = *reinterpret_cast<const half4*>(&bw);
      acc[c] = __builtin_amdgcn_mfma_f32_16x16x16f16(af, bf, acc[c], 0, 0, 0);
    }
  }
  __syncthreads();

  if (CONV) {
#pragma unroll
    for (int c = 0; c < 8; ++c)
#pragma unroll
      for (int rg = 0; rg < 4; ++rg)
        ldsb[(w*16 + ((l>>4)<<2) + rg) * 136 + c*16 + (l & 15)] = (_Float16)acc[c][rg];
    if ((l & 15) < 2) {
      float* dst = ((l & 15) == 0) ? asrc : adst;
#pragma unroll
      for (int rg = 0; rg < 4; ++rg) {
        int r = r0 + w*16 + ((l>>4)<<2) + rg;
        if (r < N) dst[r] = acc[8][rg];
      }
    }
    __syncthreads();
    _Float16* H = (_Float16*)Hout;
    for (int v = t; v < 1024; v += 256) {
      int row = v >> 4, q = v & 15;
      int r = r0 + row;
      if (r < N)
        *(uint4*)(H + (size_t)r * 128 + q * 8) = *(const uint4*)(&ldsb[row * 136 + q * 8]);
    }
  } else {
    float* ldsf = (float*)ldsb;  // [64][68]
#pragma unroll
    for (int c = 0; c < 4; ++c)
#pragma unroll
      for (int rg = 0; rg < 4; ++rg)
        ldsf[(w*16 + ((l>>4)<<2) + rg) * 68 + c*16 + (l & 15)] = acc[c][rg];
    __syncthreads();
    float* O = (float*)Hout;
    for (int v = t; v < 1024; v += 256) {
      int row = v >> 4, q = v & 15;
      int r = r0 + row;
      if (r < N) {
        float4 o = *(const float4*)(&ldsf[row * 68 + q * 4]);
        float4 bb = *(const float4*)(bias + q * 4);
        o.x += bb.x; o.y += bb.y; o.z += bb.z; o.w += bb.w;
        *(float4*)(O + (size_t)r * 64 + q * 4) = o;
      }
    }
  }
}

// ---------- phase0: bucket fill + both layer-0 GEMMs, interleaved ----------
__global__ __launch_bounds__(256) void phase0_kernel(
    const float* __restrict__ xu, const float* __restrict__ xi,
    const uint2* __restrict__ Wfc,
    _Float16* __restrict__ hs_u, _Float16* __restrict__ hs_i,
    float* __restrict__ asrc_u, float* __restrict__ adst_u,
    float* __restrict__ asrc_i, float* __restrict__ adst_i,
    const int* __restrict__ ei0, const int* __restrict__ ei1,
    const float* __restrict__ ea0, const float* __restrict__ ea1,
    const float* __restrict__ pv_ae,
    int* __restrict__ cnt0, int* __restrict__ cnt1,
    uint2* __restrict__ bkt0, uint2* __restrict__ bkt1,
    int N, int E, int gB, int P, int gEf)
{
  __shared__ __align__(16) _Float16 ldsb[64 * 136];
  int b = blockIdx.x, t = threadIdx.x;
  int g = b / P, r = b - g * P;
  if (r == 0) {  // g in [0, 2*gB)
    if (g < gB)
      gemm_body<true, true>(ldsb, g, t, xu, Wfc, hs_u, asrc_u, adst_u, nullptr, N);
    else
      gemm_body<true, true>(ldsb, g - gB, t, xi, Wfc + 4608, hs_i, asrc_i, adst_i, nullptr, N);
  } else {
    int fid = b - g - 1;
    if (fid < 2 * gEf)
      fill_body(fid, t, ei0, ei1, ea0, ea1, pv_ae, cnt0, cnt1, bkt0, bkt1, E, gEf);
  }
}

// ---------- fused GEMM pair ----------
template<bool FIN, bool CONV>
__global__ __launch_bounds__(256) void gemm_pair_kernel(
    const void* __restrict__ X0, const void* __restrict__ X1,
    const uint2* __restrict__ Wf0, const uint2* __restrict__ Wf1,
    void* __restrict__ H0, void* __restrict__ H1,
    float* __restrict__ asrc0, float* __restrict__ adst0,
    float* __restrict__ asrc1, float* __restrict__ adst1,
    const float* __restrict__ bias0, const float* __restrict__ bias1,
    int N, int gB)
{
  __shared__ __align__(16) _Float16 ldsb[64 * 136];
  int b = blockIdx.x;
  if (b < gB)
    gemm_body<FIN, CONV>(ldsb, b, threadIdx.x, X0, Wf0, H0, asrc0, adst0, bias0, N);
  else
    gemm_body<FIN, CONV>(ldsb, b - gB, threadIdx.x, X1, Wf1, H1, asrc1, adst1, bias1, N);
}

// ---------- fused aggregate pair: 16B/lane gathers, 4 edges per load ----------
__global__ __launch_bounds__(256) void aggregate_pair(
    const int* __restrict__ cnt0, const uint2* __restrict__ bkt0,
    const float* __restrict__ asrc0, const float* __restrict__ adst0,
    const __half2* __restrict__ hs0, const float* __restrict__ bias0,
    __half2* __restrict__ out0,
    const int* __restrict__ cnt1, const uint2* __restrict__ bkt1,
    const float* __restrict__ asrc1, const float* __restrict__ adst1,
    const __half2* __restrict__ hs1, const float* __restrict__ bias1,
    __half2* __restrict__ out1,
    int N, int lsel, int gHalf)
{
  int b = blockIdx.x;
  int tt = (b >= gHalf) ? 1 : 0;
  const int* cnt_tab    = tt ? cnt1 : cnt0;
  const uint2* bkt      = tt ? bkt1 : bkt0;
  const float* asrc_tab = tt ? asrc1 : asrc0;
  const float* adst_tab = tt ? adst1 : adst0;
  const uint4* hs4      = (const uint4*)(tt ? hs1 : hs0);  // row = 16 uint4
  const float* bias     = tt ? bias1 : bias0;
  __half2* xnew         = tt ? out1 : out0;

  int wid = threadIdx.x >> 6, lane = threadIdx.x & 63;
  int n = (b - tt * gHalf) * 4 + wid;
  if (n >= N) return;
  int cnt = cnt_tab[n]; if (cnt > KCAP) cnt = KCAP;
  float adst = adst_tab[n];

  // one bucket entry per lane (cnt <= KCAP=48 <= 64)
  int r = 0; float wgt = 0.f;
  if (lane < cnt) {
    uint2 sv = bkt[(size_t)n * KCAP + lane];
    r = (int)sv.x;
    __half2 hh = *(const __half2*)&sv.y;
    float ae = lsel ? __high2float(hh) : __low2float(hh);
    float al = asrc_tab[r] + adst + ae;
    al = (al > 0.f) ? al : 0.2f * al;
    wgt = __expf(al);
  }

  const int quarter = lane >> 4;   // which of 4 edges this lane serves
  const int j = lane & 15;         // uint4 column (8 halfs)
  float acc[8];
#pragma unroll
  for (int q = 0; q < 8; ++q) acc[q] = 0.f;

  int k = 0;
  for (; k + 8 <= cnt; k += 8) {
    int   rr0 = __shfl(r,   k + quarter);
    float ww0 = __shfl(wgt, k + quarter);
    int   rr1 = __shfl(r,   k + 4 + quarter);
    float ww1 = __shfl(wgt, k + 4 + quarter);
    uint4 v0 = hs4[(size_t)rr0 * 16 + j];
    uint4 v1 = hs4[(size_t)rr1 * 16 + j];
    float2 f;
    f = __half22float2(*(const __half2*)&v0.x); acc[0]=fmaf(ww0,f.x,acc[0]); acc[1]=fmaf(ww0,f.y,acc[1]);
    f = __half22float2(*(const __half2*)&v0.y); acc[2]=fmaf(ww0,f.x,acc[2]); acc[3]=fmaf(ww0,f.y,acc[3]);
    f = __half22float2(*(const __half2*)&v0.z); acc[4]=fmaf(ww0,f.x,acc[4]); acc[5]=fmaf(ww0,f.y,acc[5]);
    f = __half22float2(*(const __half2*)&v0.w); acc[6]=fmaf(ww0,f.x,acc[6]); acc[7]=fmaf(ww0,f.y,acc[7]);
    f = __half22float2(*(const __half2*)&v1.x); acc[0]=fmaf(ww1,f.x,acc[0]); acc[1]=fmaf(ww1,f.y,acc[1]);
    f = __half22float2(*(const __half2*)&v1.y); acc[2]=fmaf(ww1,f.x,acc[2]); acc[3]=fmaf(ww1,f.y,acc[3]);
    f = __half22float2(*(const __half2*)&v1.z); acc[4]=fmaf(ww1,f.x,acc[4]); acc[5]=fmaf(ww1,f.y,acc[5]);
    f = __half22float2(*(const __half2*)&v1.w); acc[6]=fmaf(ww1,f.x,acc[6]); acc[7]=fmaf(ww1,f.y,acc[7]);
  }
  for (; k < cnt; k += 4) {
    // lanes whose edge index k+quarter >= cnt read lane with wgt==0 -> no-op
    int   rr = __shfl(r,   k + quarter);
    float ww = __shfl(wgt, k + quarter);
    uint4 v = hs4[(size_t)rr * 16 + j];
    float2 f;
    f = __half22float2(*(const __half2*)&v.x); acc[0]=fmaf(ww,f.x,acc[0]); acc[1]=fmaf(ww,f.y,acc[1]);
    f = __half22float2(*(const __half2*)&v.y); acc[2]=fmaf(ww,f.x,acc[2]); acc[3]=fmaf(ww,f.y,acc[3]);
    f = __half22float2(*(const __half2*)&v.z); acc[4]=fmaf(ww,f.x,acc[4]); acc[5]=fmaf(ww,f.y,acc[5]);
    f = __half22float2(*(const __half2*)&v.w); acc[6]=fmaf(ww,f.x,acc[6]); acc[7]=fmaf(ww,f.y,acc[7]);
  }

#pragma unroll
  for (int q = 0; q < 8; ++q) {
    acc[q] += __shfl_xor(acc[q], 16);
    acc[q] += __shfl_xor(acc[q], 32);
  }
  float den = wave_sum(wgt);
  float inv = (den > 0.f) ? 1.f / den : 0.f;

  if (quarter == 0) {
    float4 b0 = *(const float4*)(bias + 8*j);
    float4 b1 = *(const float4*)(bias + 8*j + 4);
    float o0 = fmaxf(fmaf(acc[0], inv, b0.x), 0.f);
    float o1 = fmaxf(fmaf(acc[1], inv, b0.y), 0.f);
    float o2 = fmaxf(fmaf(acc[2], inv, b0.z), 0.f);
    float o3 = fmaxf(fmaf(acc[3], inv, b0.w), 0.f);
    float o4 = fmaxf(fmaf(acc[4], inv, b1.x), 0.f);
    float o5 = fmaxf(fmaf(acc[5], inv, b1.y), 0.f);
    float o6 = fmaxf(fmaf(acc[6], inv, b1.z), 0.f);
    float o7 = fmaxf(fmaf(acc[7], inv, b1.w), 0.f);
    __half2 p0 = __floats2half2_rn(o0, o1);
    __half2 p1 = __floats2half2_rn(o2, o3);
    __half2 p2 = __floats2half2_rn(o4, o5);
    __half2 p3 = __floats2half2_rn(o6, o7);
    uint4 wv;
    wv.x = *(const unsigned*)&p0; wv.y = *(const unsigned*)&p1;
    wv.z = *(const unsigned*)&p2; wv.w = *(const unsigned*)&p3;
    ((uint4*)xnew)[(size_t)n * 16 + j] = wv;
  }
}

// ---------------------------------------------------------------------------
extern "C" void kernel_launch(void* const* d_in, const int* in_sizes, int n_in,
                              void* d_out, int out_size, void* d_ws, size_t ws_size,
                              hipStream_t stream)
{
  const float* x_user   = (const float*)d_in[0];
  const float* x_item   = (const float*)d_in[1];
  const float* ea_ui    = (const float*)d_in[2];
  const float* ea_iu    = (const float*)d_in[3];
  const float* W_src    = (const float*)d_in[4];
  const float* W_dst    = (const float*)d_in[5];
  const float* W_edge   = (const float*)d_in[6];
  const float* att_src  = (const float*)d_in[7];
  const float* att_dst  = (const float*)d_in[8];
  const float* att_edge = (const float*)d_in[9];
  const float* conv_bias= (const float*)d_in[10];
  const float* lin0W    = (const float*)d_in[11];
  const float* lin0b    = (const float*)d_in[12];
  const float* lin1W    = (const float*)d_in[13];
  const float* lin1b    = (const float*)d_in[14];
  const int*   ei_ui    = (const int*)d_in[15];
  const int*   ei_iu    = (const int*)d_in[16];

  const int N = in_sizes[0] / 128;
  const int E = in_sizes[15] / 2;

  char* p = (char*)d_ws;
  auto alloc = [&](size_t bytes) -> void* {
    void* r = (void*)p;
    p += (bytes + 255) & ~(size_t)255;
    return r;
  };
  _Float16* xu_a = (_Float16*)alloc((size_t)N * 128 * 2);
  _Float16* xi_a = (_Float16*)alloc((size_t)N * 128 * 2);
  _Float16* xu_b = (_Float16*)alloc((size_t)N * 128 * 2);
  _Float16* xi_b = (_Float16*)alloc((size_t)N * 128 * 2);
  _Float16* hs_u = (_Float16*)alloc((size_t)N * 128 * 2);
  _Float16* hs_i = (_Float16*)alloc((size_t)N * 128 * 2);
  uint2* bkt_ui  = (uint2*)alloc((size_t)N * KCAP * 8);
  uint2* bkt_iu  = (uint2*)alloc((size_t)N * KCAP * 8);
  int*   cnt_ui  = (int*)alloc((size_t)2 * N * 4);
  int*   cnt_iu  = cnt_ui + N;
  float* asrc_u  = (float*)alloc((size_t)N * 4);
  float* adst_u  = (float*)alloc((size_t)N * 4);
  float* asrc_i  = (float*)alloc((size_t)N * 4);
  float* adst_i  = (float*)alloc((size_t)N * 4);
  float* pv_as   = (float*)alloc(512 * 4);
  float* pv_ad   = (float*)alloc(512 * 4);
  float* pv_ae   = (float*)alloc(64 * 4);
  float* Wc      = (float*)alloc(2 * 128 * 64 * 4);
  float* bc      = (float*)alloc(128 * 4);
  _Float16* Wf_conv = (_Float16*)alloc(73728 * 2);
  _Float16* Wf_mlp  = (_Float16*)alloc(16384 * 2);

  // prep
  precompute_vec_kernel<<<4 * 272, 64, 0, stream>>>(W_src, W_dst, W_edge,
      att_src, att_dst, att_edge, pv_as, pv_ad, pv_ae);
  combine_linear_kernel<<<65, 256, 0, stream>>>(lin0W, lin0b, lin1W, lin1b, Wc, bc);
  wfrag_prep_kernel<<<352, 256, 0, stream>>>(W_src, pv_as, pv_ad, Wc, Wf_conv, Wf_mlp);
  hipMemsetAsync(cnt_ui, 0, (size_t)2 * N * 4, stream);

  const int gEf = (E + 255) / 256;
  const int gB  = (N + 63) / 64;
  const int GB2 = 2 * gB;
  const int P   = 1 + (2 * gEf + GB2 - 1) / GB2;   // 1 gemm block per (P-1) fill blocks
  const int gN4 = (N + 3) / 4;
  const uint2* Wfc = (const uint2*)Wf_conv;
  const uint2* Wfm = (const uint2*)Wf_mlp;

  // ---- phase 0: bucket fill + layer-0 GEMMs ----
  phase0_kernel<<<P * GB2, 256, 0, stream>>>(x_user, x_item, Wfc,
      hs_u, hs_i, asrc_u, adst_u, asrc_i, adst_i,
      ei_ui, ei_iu, ea_ui, ea_iu, pv_ae, cnt_ui, cnt_iu, bkt_ui, bkt_iu,
      N, E, gB, P, gEf);

  // ---- layer 0 aggregates (both types) ----
  aggregate_pair<<<2 * gN4, 256, 0, stream>>>(
      cnt_ui, bkt_ui, asrc_u, adst_i, (const __half2*)hs_u, conv_bias + 0*128, (__half2*)xi_a,
      cnt_iu, bkt_iu, asrc_i, adst_u, (const __half2*)hs_i, conv_bias + 1*128, (__half2*)xu_a,
      N, 0, gN4);

  // ---- layer 1 GEMMs (both types) ----
  gemm_pair_kernel<false, true><<<GB2, 256, 0, stream>>>(
      xu_a, xi_a, Wfc + 2*4608, Wfc + 3*4608, hs_u, hs_i,
      asrc_u, adst_u, asrc_i, adst_i, nullptr, nullptr, N, gB);

  // ---- layer 1 aggregates ----
  aggregate_pair<<<2 * gN4, 256, 0, stream>>>(
      cnt_ui, bkt_ui, asrc_u, adst_i, (const __half2*)hs_u, conv_bias + 2*128, (__half2*)xi_b,
      cnt_iu, bkt_iu, asrc_i, adst_u, (const __half2*)hs_i, conv_bias + 3*128, (__half2*)xu_b,
      N, 1, gN4);

  // ---- fused output MLP (both types) ----
  float* out = (float*)d_out;
  gemm_pair_kernel<false, false><<<GB2, 256, 0, stream>>>(
      xu_b, xi_b, Wfm, Wfm + 2048, out, out + (size_t)N * 64,
      nullptr, nullptr, nullptr, nullptr, bc, bc + 64, N, gB);
}